// Round 2
// baseline (174.707 us; speedup 1.0000x reference)
//
#include <hip/hip_runtime.h>

// Problem constants (fixed by setup_inputs)
#define B_ 8
#define N_ 16384
#define C_ 64
#define S_ 5

typedef float v4f __attribute__((ext_vector_type(4)));
typedef __bf16 v8bf __attribute__((ext_vector_type(8)));
typedef unsigned int v4u __attribute__((ext_vector_type(4)));

// fp32 -> bf16 bits, round-to-nearest-even (finite inputs only)
static __device__ __forceinline__ unsigned short f2bf(float f) {
    unsigned int u = __float_as_uint(f);
    u += 0x7fffu + ((u >> 16) & 1u);
    return (unsigned short)(u >> 16);
}
static __device__ __forceinline__ float bf2f(unsigned short s) {
    return __uint_as_float(((unsigned int)s) << 16);
}

// ---------------------------------------------------------------------------
// Kernel 1: weight prep (block 0) + fg_xyz passthrough copy (blocks 1..96).
// Folds BN scale s = g*rsqrt(v+1e-5) into the weights:
//   Wa' = s1 .* W1[:, :64]   (bf16)   Wc' = s1 .* (W1a+W1b)   (bf16)
//   W2' = s2 .* W2           (bf16)   w1bs = s1 .* W1[:, 64:] (fp32)
//   bb1 = b1 - m1*s1, bb2 = b2 - m2*s2
// ---------------------------------------------------------------------------
__global__ __launch_bounds__(256) void prep_w_copy(
    const float* __restrict__ w1, const float* __restrict__ g1, const float* __restrict__ b1,
    const float* __restrict__ m1, const float* __restrict__ v1,
    const float* __restrict__ w2, const float* __restrict__ g2, const float* __restrict__ b2,
    const float* __restrict__ m2, const float* __restrict__ v2,
    float* __restrict__ w1bs, float* __restrict__ bb1, float* __restrict__ bb2,
    unsigned short* __restrict__ wa_bf, unsigned short* __restrict__ wc_bf,
    unsigned short* __restrict__ w2_bf,
    const float* __restrict__ fg_xyz, float* __restrict__ out_xyz) {
    const int t = threadIdx.x;
    const int blk = blockIdx.x;
    if (blk > 0) {
        // copy 4096 floats = 1024 float4 per block
        const float4* src = (const float4*)(fg_xyz + (size_t)(blk - 1) * 4096);
        float4* dst = (float4*)(out_xyz + (size_t)(blk - 1) * 4096);
#pragma unroll
        for (int i = 0; i < 4; ++i) dst[t + i * 256] = src[t + i * 256];
        return;
    }
    for (int i = t; i < 64 * 64; i += 256) {
        const int o = i >> 6, c = i & 63;
        const float s1 = g1[o] / sqrtf(v1[o] + 1e-5f);
        const float s2 = g2[o] / sqrtf(v2[o] + 1e-5f);
        const float a = s1 * w1[o * 128 + c];
        const float bb = s1 * w1[o * 128 + 64 + c];
        w1bs[o * 64 + c] = bb;
        wa_bf[o * 64 + c] = f2bf(a);
        wc_bf[o * 64 + c] = f2bf(a + bb);
        w2_bf[o * 64 + c] = f2bf(s2 * w2[o * 64 + c]);
    }
    if (t < 64) {
        const float s1 = g1[t] / sqrtf(v1[t] + 1e-5f);
        const float s2 = g2[t] / sqrtf(v2[t] + 1e-5f);
        bb1[t] = b1[t] - m1[t] * s1;
        bb2[t] = b2[t] - m2[t] * s2;
    }
}

// ---------------------------------------------------------------------------
// Kernel 2: farthest point sampling + sampled-bg constant build.
// One block per batch; dists+xyz in registers (512 thr x 32 pts). Matches
// jax scan semantics: idx[0]=0, then argmax (FIRST max index) of running min.
// Tail (fused, was prep_sbg):
//   sbg[b][j][c] = bg_features[b, c, idx_j]
//   ebb[b][j][o] = sum_c w1bs[o,c]*sbg[b,j,c] + bb1[o]
// ---------------------------------------------------------------------------
__global__ __launch_bounds__(512) void fps_sbg(
    const float* __restrict__ xyz, const float* __restrict__ bg_feat,
    const float* __restrict__ w1bs, const float* __restrict__ bb1,
    float* __restrict__ sbg, float* __restrict__ ebb) {
    const int b = blockIdx.x;
    const float* p = xyz + (size_t)b * N_ * 3;
    const int t = threadIdx.x;
    const int PPT = N_ / 512; // 32

    float px[PPT], py[PPT], pz[PPT], dist[PPT];
#pragma unroll
    for (int k = 0; k < PPT; ++k) {
        int i = t + k * 512;
        px[k] = p[i * 3 + 0];
        py[k] = p[i * 3 + 1];
        pz[k] = p[i * 3 + 2];
        dist[k] = 1e10f;
    }

    __shared__ float s_best[8];
    __shared__ int s_bidx[8];
    __shared__ int s_last;
    __shared__ int s_idx[S_];
    __shared__ float sf[S_][64];
    int last = 0;
    if (t == 0) s_idx[0] = 0;

    for (int step = 1; step < S_; ++step) {
        const float lx = p[last * 3 + 0];
        const float ly = p[last * 3 + 1];
        const float lz = p[last * 3 + 2];
        float best = -1.0f;
        int bidx = 0;
#pragma unroll
        for (int k = 0; k < PPT; ++k) {
            float dx = px[k] - lx, dy = py[k] - ly, dz = pz[k] - lz;
            float d = dx * dx + dy * dy + dz * dz;
            float nd = fminf(dist[k], d);
            dist[k] = nd;
            if (nd > best) { best = nd; bidx = t + k * 512; } // strict > -> lowest idx in-thread
        }
#pragma unroll
        for (int off = 32; off > 0; off >>= 1) {
            float ob = __shfl_down(best, off, 64);
            int oi = __shfl_down(bidx, off, 64);
            if (ob > best || (ob == best && oi < bidx)) { best = ob; bidx = oi; }
        }
        if ((t & 63) == 0) { s_best[t >> 6] = best; s_bidx[t >> 6] = bidx; }
        __syncthreads();
        if (t == 0) {
            float bb = s_best[0];
            int bi = s_bidx[0];
#pragma unroll
            for (int w = 1; w < 8; ++w) {
                if (s_best[w] > bb || (s_best[w] == bb && s_bidx[w] < bi)) {
                    bb = s_best[w];
                    bi = s_bidx[w];
                }
            }
            s_last = bi;
            s_idx[step] = bi;
        }
        __syncthreads();
        last = s_last;
        __syncthreads(); // protect s_best from next-iteration overwrite
    }

    // ---- fused sbg/ebb build ----
    if (t < S_ * 64) {
        const int j = t >> 6, c = t & 63;
        sf[j][c] = bg_feat[(size_t)b * C_ * N_ + (size_t)c * N_ + s_idx[j]];
    }
    __syncthreads();
    if (t < S_ * 64) {
        const int j = t >> 6, o = t & 63;
        const float4* wr = (const float4*)&w1bs[o * 64];
        float acc = 0.f;
#pragma unroll
        for (int c4 = 0; c4 < 16; ++c4) {
            float4 wv = wr[c4];
            acc += wv.x * sf[j][c4 * 4 + 0] + wv.y * sf[j][c4 * 4 + 1] +
                   wv.z * sf[j][c4 * 4 + 2] + wv.w * sf[j][c4 * 4 + 3];
        }
        sbg[(b * S_ + j) * 64 + o] = sf[j][o];
        ebb[(b * S_ + j) * 64 + o] = acc + bb1[o];
    }
}

// ---------------------------------------------------------------------------
// Kernel 3: main fused MLP — ONE barrier total.
// Wave partitioning over n: wave w owns columns n0+16w..+15 and computes ALL
// 64 output channels for them. H (layer-1 out) for those columns lives
// entirely in the wave -> C-layout -> B-frag transform is a WAVE-PRIVATE LDS
// round-trip (no __syncthreads; same-wave LDS ops are ordered, compiler
// inserts lgkmcnt). Ht double-buffered on slice parity (WAR safety).
// MFMA layouts (HW-verified): A[m=lane&15][k=(lane>>4)*8+j];
// C/D: col=lane&15, row=(lane>>4)*4+reg.
// ---------------------------------------------------------------------------
#define PITCH 72 // shorts per LDS row (36 words): optimal bank spread for b64/b128

__global__ __launch_bounds__(256) void fusion_main(
    const float* __restrict__ fg_feat,
    const unsigned short* __restrict__ wa_bf, const unsigned short* __restrict__ wc_bf,
    const unsigned short* __restrict__ w2_bf,
    const float* __restrict__ bb1g, const float* __restrict__ bb2g,
    const float* __restrict__ ebbg, const float* __restrict__ sbgg,
    float* __restrict__ out) {
    __shared__ __align__(16) unsigned short Ft[64 * PITCH];
    __shared__ __align__(16) unsigned short Ht[2][4][16 * PITCH];
    __shared__ __align__(16) float cEbb[S_ * 64];
    __shared__ __align__(16) float cSbg[S_ * 64];
    __shared__ __align__(16) float cBb1[64];
    __shared__ __align__(16) float cBb2[64];

    const int t = threadIdx.x;
    const int b = blockIdx.y;
    const int n0 = blockIdx.x * 64;
    const float* Fg = fg_feat + (size_t)b * C_ * N_ + n0;

    // ---- stage F tile transposed (bf16) into Ft[n][c] ----
    {
        const int n = t & 63;
        const int cg = (t >> 6) * 16;
        v4u w0, w1v;
#pragma unroll
        for (int i = 0; i < 8; ++i) {
            unsigned short lo = f2bf(Fg[(size_t)(cg + 2 * i) * N_ + n]);
            unsigned short hi = f2bf(Fg[(size_t)(cg + 2 * i + 1) * N_ + n]);
            unsigned int packed = (unsigned int)lo | ((unsigned int)hi << 16);
            if (i < 4) w0[i] = packed; else w1v[i - 4] = packed;
        }
        *(v4u*)&Ft[n * PITCH + cg] = w0;
        *(v4u*)&Ft[n * PITCH + cg + 8] = w1v;
    }
    // ---- stage per-(b,slice) constants ----
    for (int i = t; i < S_ * 64; i += 256) {
        cEbb[i] = ebbg[b * (S_ * 64) + i];
        cSbg[i] = sbgg[b * (S_ * 64) + i];
    }
    if (t < 64) { cBb1[t] = bb1g[t]; cBb2[t] = bb2g[t]; }

    const int lane = t & 63;
    const int w = t >> 6;      // wave id -> n-block
    const int m = lane & 15;   // A row / B col / D col
    const int q = lane >> 4;   // k-chunk / D row-group
    const int nrow = w * 16 + m; // this lane's n column (local)

    // A-fragments straight from global (small, L2-resident). Wave computes
    // all 4 o-blocks.
    v8bf aWa[4][2], aWc[4][2], aW2[4][2];
#pragma unroll
    for (int ob = 0; ob < 4; ++ob)
#pragma unroll
        for (int ks = 0; ks < 2; ++ks) {
            const int widx = (ob * 16 + m) * 64 + ks * 32 + q * 8;
            aWa[ob][ks] = *(const v8bf*)&wa_bf[widx];
            aWc[ob][ks] = *(const v8bf*)&wc_bf[widx];
            aW2[ob][ks] = *(const v8bf*)&w2_bf[widx];
        }

    __syncthreads(); // the ONLY barrier: Ft + constants ready

    // B-fragments of F (this wave's 16 columns)
    v8bf bF[2];
#pragma unroll
    for (int ks = 0; ks < 2; ++ks)
        bF[ks] = *(const v8bf*)&Ft[nrow * PITCH + ks * 32 + q * 8];

    // GEMM1: U = Wa'.F (slices>=1), U0 = Wc'.F (slice 0)
    v4f U[4], U0[4];
#pragma unroll
    for (int ob = 0; ob < 4; ++ob) {
        v4f z = {0.f, 0.f, 0.f, 0.f};
        z = __builtin_amdgcn_mfma_f32_16x16x32_bf16(aWa[ob][0], bF[0], z, 0, 0, 0);
        U[ob] = __builtin_amdgcn_mfma_f32_16x16x32_bf16(aWa[ob][1], bF[1], z, 0, 0, 0);
        v4f z2 = {0.f, 0.f, 0.f, 0.f};
        z2 = __builtin_amdgcn_mfma_f32_16x16x32_bf16(aWc[ob][0], bF[0], z2, 0, 0, 0);
        U0[ob] = __builtin_amdgcn_mfma_f32_16x16x32_bf16(aWc[ob][1], bF[1], z2, 0, 0, 0);
    }

    v4f acc[4];
#pragma unroll
    for (int ob = 0; ob < 4; ++ob) acc[ob] = (v4f){0.f, 0.f, 0.f, 0.f};

#pragma unroll
    for (int s = 0; s < 6; ++s) {
        unsigned short* h = &Ht[s & 1][w][0]; // wave-private, double-buffered

        // form H (C-layout) -> write transposed into wave-private Ht[n16][c]
#pragma unroll
        for (int ob = 0; ob < 4; ++ob) {
            const int o4 = ob * 16 + 4 * q;
            v4f cv, u;
            if (s == 0) { cv = *(const v4f*)&cBb1[o4]; u = U0[ob]; }
            else        { cv = *(const v4f*)&cEbb[(s - 1) * 64 + o4]; u = U[ob]; }
            unsigned int lo = (unsigned int)f2bf(fmaxf(u[0] + cv[0], 0.f)) |
                              ((unsigned int)f2bf(fmaxf(u[1] + cv[1], 0.f)) << 16);
            unsigned int hi = (unsigned int)f2bf(fmaxf(u[2] + cv[2], 0.f)) |
                              ((unsigned int)f2bf(fmaxf(u[3] + cv[3], 0.f)) << 16);
            unsigned long long v = (unsigned long long)lo | ((unsigned long long)hi << 32);
            *(unsigned long long*)&h[m * PITCH + o4] = v;
        }

        // read B-frags of H (same wave wrote them; LDS per-wave ordering +
        // compiler lgkmcnt cover the dependency — no barrier)
        v8bf hb0 = *(const v8bf*)&h[m * PITCH + q * 8];
        v8bf hb1 = *(const v8bf*)&h[m * PITCH + 32 + q * 8];

        // GEMM2 + epilogue: acc += relu(p + bb2) * multiplier
#pragma unroll
        for (int ob = 0; ob < 4; ++ob) {
            v4f z = {0.f, 0.f, 0.f, 0.f};
            z = __builtin_amdgcn_mfma_f32_16x16x32_bf16(aW2[ob][0], hb0, z, 0, 0, 0);
            v4f p = __builtin_amdgcn_mfma_f32_16x16x32_bf16(aW2[ob][1], hb1, z, 0, 0, 0);

            const int o4 = ob * 16 + 4 * q;
            const v4f b2v = *(const v4f*)&cBb2[o4];
            if (s == 0) {
                unsigned long long fv = *(const unsigned long long*)&Ft[nrow * PITCH + o4];
#pragma unroll
                for (int r = 0; r < 4; ++r) {
                    float wgt = fmaxf(p[r] + b2v[r], 0.f);
                    acc[ob][r] += wgt * bf2f((unsigned short)(fv >> (16 * r)));
                }
            } else {
                const v4f sb = *(const v4f*)&cSbg[(s - 1) * 64 + o4];
#pragma unroll
                for (int r = 0; r < 4; ++r) {
                    float wgt = fmaxf(p[r] + b2v[r], 0.f);
                    acc[ob][r] += wgt * sb[r];
                }
            }
        }
    }

    // store: out[b][o][n], o = ob*16+4q+r, n = n0 + w*16 + m
#pragma unroll
    for (int ob = 0; ob < 4; ++ob)
#pragma unroll
        for (int r = 0; r < 4; ++r)
            out[(size_t)b * C_ * N_ + (size_t)(ob * 16 + 4 * q + r) * N_ + (n0 + w * 16 + m)] =
                acc[ob][r];
}

// ---------------------------------------------------------------------------
extern "C" void kernel_launch(void* const* d_in, const int* in_sizes, int n_in,
                              void* d_out, int out_size, void* d_ws, size_t ws_size,
                              hipStream_t stream) {
    const float* fg_xyz = (const float*)d_in[0];
    const float* fg_feat = (const float*)d_in[1];
    const float* bg_xyz = (const float*)d_in[2];
    const float* bg_feat = (const float*)d_in[3];
    const float* w1 = (const float*)d_in[4];
    const float* g1 = (const float*)d_in[5];
    const float* b1 = (const float*)d_in[6];
    const float* m1 = (const float*)d_in[7];
    const float* v1 = (const float*)d_in[8];
    const float* w2 = (const float*)d_in[9];
    const float* g2 = (const float*)d_in[10];
    const float* b2 = (const float*)d_in[11];
    const float* m2 = (const float*)d_in[12];
    const float* v2 = (const float*)d_in[13];

    // workspace layout (float units)
    float* ws = (float*)d_ws;
    float* w1bs = ws;                       // 4096
    float* ebb = w1bs + 4096;               // 2560
    float* sbg = ebb + 2560;                // 2560
    float* bb1 = sbg + 2560;                // 64
    float* bb2 = bb1 + 64;                  // 64
    unsigned short* wa_bf = (unsigned short*)(bb2 + 64); // 4096 shorts
    unsigned short* wc_bf = wa_bf + 4096;
    unsigned short* w2_bf = wc_bf + 4096;

    float* out_feats = (float*)d_out + (size_t)B_ * N_ * 3;

    // node 1: weight prep (block 0) + fg_xyz passthrough (blocks 1..96)
    prep_w_copy<<<97, 256, 0, stream>>>(w1, g1, b1, m1, v1, w2, g2, b2, m2, v2,
                                        w1bs, bb1, bb2, wa_bf, wc_bf, w2_bf,
                                        fg_xyz, (float*)d_out);
    // node 2: FPS + sampled-bg constants (needs w1bs/bb1 -> stream order)
    fps_sbg<<<B_, 512, 0, stream>>>(bg_xyz, bg_feat, w1bs, bb1, sbg, ebb);
    // node 3: fused MLP
    fusion_main<<<dim3(N_ / 64, B_), 256, 0, stream>>>(
        fg_feat, wa_bf, wc_bf, w2_bf, bb1, bb2, ebb, sbg, out_feats);
}